// Round 1
// baseline (1364.856 us; speedup 1.0000x reference)
//
#include <hip/hip_runtime.h>
#include <math.h>

#define S_ 64
#define H_ 256
#define NH_ 4
#define DH_ 64
#define I_ 512
#define L_ 2

typedef __attribute__((ext_vector_type(8))) short short8;
typedef __attribute__((ext_vector_type(4))) short short4v;
typedef __attribute__((ext_vector_type(4))) float f32x4;

__device__ __forceinline__ unsigned short f2b(float f) {
  unsigned u = __float_as_uint(f);
  return (unsigned short)((u + 0x7fffu + ((u >> 16) & 1u)) >> 16);
}
__device__ __forceinline__ float b2f(unsigned short h) {
  return __uint_as_float(((unsigned)h) << 16);
}
__device__ __forceinline__ f32x4 mfma16(short8 a, short8 b, f32x4 c) {
  return __builtin_amdgcn_mfma_f32_16x16x32_bf16(a, b, c, 0, 0, 0);
}
// XOR-swizzled LDS tiles: element (row,col) lives at (row*STRIDE+col)^((row&7)<<3)
// (16B-chunk swizzle; all vector accesses are exactly one 8-element chunk).
template <int STRIDE>
__device__ __forceinline__ short8 lds8(const short* buf, int row, int k) {
  int idx = (row * STRIDE + k) ^ ((row & 7) << 3);
  return *(const short8*)(buf + idx);
}
template <int STRIDE>
__device__ __forceinline__ void ldsw(short* buf, int row, int col, unsigned short v) {
  buf[(row * STRIDE + col) ^ ((row & 7) << 3)] = (short)v;
}
__device__ __forceinline__ float red16sum(float v) {
  v += __shfl_xor(v, 1); v += __shfl_xor(v, 2);
  v += __shfl_xor(v, 4); v += __shfl_xor(v, 8);
  return v;
}
__device__ __forceinline__ float red16max(float v) {
  v = fmaxf(v, __shfl_xor(v, 1)); v = fmaxf(v, __shfl_xor(v, 2));
  v = fmaxf(v, __shfl_xor(v, 4)); v = fmaxf(v, __shfl_xor(v, 8));
  return v;
}

// ---- weight prep: f32 [K][N] -> bf16 WT[N][K] (per layer), packed into ws ----
// layout (shorts): wq[0..131072) wk wv wo (131072 each), wi at 524288 (262144),
// wout at 786432 (262144). Per-layer strides: H*H=65536, I*H=131072, H*I=131072.
__global__ void prep_w(const float* __restrict__ qw, const float* __restrict__ kw,
                       const float* __restrict__ vw, const float* __restrict__ ow,
                       const float* __restrict__ iw, const float* __restrict__ outw,
                       short* __restrict__ ws) {
  int t = blockIdx.x * 256 + threadIdx.x;  // 1,048,576 total
  if (t < 524288) {
    int which = t >> 17;
    int r = t & 131071;
    int l = r >> 16, rr = r & 65535;
    int col = rr >> 8, k = rr & 255;
    const float* m = which == 0 ? qw : which == 1 ? kw : which == 2 ? vw : ow;
    ws[t] = (short)f2b(m[(l * 256 + k) * 256 + col]);
  } else if (t < 786432) {
    int tp = t - 524288;
    int l = tp >> 17, rr = tp & 131071;
    int col = rr >> 8, k = rr & 255;
    ws[t] = (short)f2b(iw[(l * 256 + k) * 512 + col]);
  } else {
    int tp = t - 786432;
    int l = tp >> 17, rr = tp & 131071;
    int col = rr >> 9, k = rr & 511;
    ws[t] = (short)f2b(outw[(l * 512 + k) * 256 + col]);
  }
}

// ---- fused BERT: 1 workgroup = 1 sequence; 4 waves; everything in LDS ----
__global__ __launch_bounds__(256, 2) void bert_fused(
    const int* __restrict__ word, const int* __restrict__ age,
    const int* __restrict__ seg, const int* __restrict__ posi,
    const float* __restrict__ mask,
    const float* __restrict__ word_emb, const float* __restrict__ seg_emb,
    const float* __restrict__ age_emb, const float* __restrict__ posi_emb,
    const float* __restrict__ emb_g, const float* __restrict__ emb_b,
    const float* __restrict__ qb, const float* __restrict__ kb,
    const float* __restrict__ vb, const float* __restrict__ ob,
    const float* __restrict__ attn_g, const float* __restrict__ attn_b,
    const float* __restrict__ ib, const float* __restrict__ outb,
    const float* __restrict__ out_g, const float* __restrict__ out_b,
    const float* __restrict__ pool_w, const float* __restrict__ pool_b,
    const short* __restrict__ wsq, const short* __restrict__ wsk,
    const short* __restrict__ wsv, const short* __restrict__ wso,
    const short* __restrict__ wsi, const short* __restrict__ wsout,
    float* __restrict__ out) {
  __shared__ __align__(16) short xb[S_ * H_];     // residual stream, bf16, swizzled
  __shared__ __align__(16) short arena[S_ * H_];  // per-phase scratch (32KB)
  __shared__ float part[2][S_][NH_];
  __shared__ float amv[S_];

  short* sQ = arena;            // 64x64
  short* sK = arena + 4096;     // 64x64
  short* sV = arena + 8192;     // VhT: [d][kseq]
  short* sP = arena + 12288;    // probs
  short* sCtx = sQ;             // reuse
  short* sH = arena;            // FFN chunk 64x128 (reuses sQ+sK)

  const int n = blockIdx.x;
  const int tid = threadIdx.x;
  const int w = tid >> 6;
  const int lane = tid & 63;
  const int l15 = lane & 15;
  const int g4 = lane >> 4;
  const f32x4 zero4 = {0.f, 0.f, 0.f, 0.f};

  if (tid < S_) amv[tid] = (1.f - mask[n * S_ + tid]) * -10000.f;

  // ---- embedding + LayerNorm: wave w handles 16 tokens, 1 row per iteration ----
  for (int i = 0; i < 16; ++i) {
    int s = w * 16 + i;
    int base = n * S_ + s;
    int wi = word[base], gi = seg[base], ai = age[base], pi = posi[base];
    f32x4 e = ((const f32x4*)(word_emb + wi * H_))[lane];
    f32x4 t = ((const f32x4*)(seg_emb + gi * H_))[lane]; e = e + t;
    t = ((const f32x4*)(age_emb + ai * H_))[lane]; e = e + t;
    t = ((const f32x4*)(posi_emb + pi * H_))[lane]; e = e + t;
    float s1 = e[0] + e[1] + e[2] + e[3];
    float s2 = e[0] * e[0] + e[1] * e[1] + e[2] * e[2] + e[3] * e[3];
    for (int m = 1; m < 64; m <<= 1) { s1 += __shfl_xor(s1, m); s2 += __shfl_xor(s2, m); }
    float mean = s1 * (1.f / H_);
    float rstd = rsqrtf(s2 * (1.f / H_) - mean * mean + 1e-12f);
    f32x4 gv = ((const f32x4*)emb_g)[lane];
    f32x4 bv = ((const f32x4*)emb_b)[lane];
    short4v pk;
#pragma unroll
    for (int j = 0; j < 4; ++j) pk[j] = (short)f2b((e[j] - mean) * rstd * gv[j] + bv[j]);
    int idx = (s * H_ + lane * 4) ^ ((s & 7) << 3);
    *(short4v*)(xb + idx) = pk;
  }
  __syncthreads();

  for (int ly = 0; ly < L_; ++ly) {
    const short* wq = wsq + ly * H_ * H_;
    const short* wk = wsk + ly * H_ * H_;
    const short* wv = wsv + ly * H_ * H_;
    const short* wo = wso + ly * H_ * H_;
    const short* wii = wsi + ly * I_ * H_;
    const short* wou = wsout + ly * H_ * I_;

    f32x4 oacc[4][4];
#pragma unroll
    for (int a = 0; a < 4; ++a)
#pragma unroll
      for (int b = 0; b < 4; ++b) oacc[a][b] = zero4;

    // ======== attention: one head per iteration, all 4 waves cooperate ========
    for (int h = 0; h < NH_; ++h) {
      // ---- Q,K,V for this head: each wave computes 16 cols x 64 rows ----
      for (int m3 = 0; m3 < 3; ++m3) {
        const short* wt = m3 == 0 ? wq : (m3 == 1 ? wk : wv);
        const float* bs = m3 == 0 ? qb : (m3 == 1 ? kb : vb);
        int colg = h * DH_ + w * 16 + l15;
        f32x4 acc[4] = {zero4, zero4, zero4, zero4};
#pragma unroll
        for (int k0 = 0; k0 < H_; k0 += 32) {
          short8 bf = *(const short8*)(wt + colg * H_ + k0 + g4 * 8);
#pragma unroll
          for (int tr = 0; tr < 4; ++tr) {
            short8 af = lds8<H_>(xb, tr * 16 + l15, k0 + g4 * 8);
            acc[tr] = mfma16(af, bf, acc[tr]);
          }
        }
        float bias = bs[ly * H_ + colg];
        if (m3 < 2) {
          short* dst = (m3 == 0) ? sQ : sK;
#pragma unroll
          for (int tr = 0; tr < 4; ++tr)
#pragma unroll
            for (int r = 0; r < 4; ++r)
              ldsw<DH_>(dst, tr * 16 + g4 * 4 + r, w * 16 + l15, f2b(acc[tr][r] + bias));
        } else {  // V transposed: [d][kseq]
#pragma unroll
          for (int tr = 0; tr < 4; ++tr)
#pragma unroll
            for (int r = 0; r < 4; ++r)
              ldsw<DH_>(sV, w * 16 + l15, tr * 16 + g4 * 4 + r, f2b(acc[tr][r] + bias));
        }
      }
      __syncthreads();

      // ---- scores + softmax: wave w owns q-rows [w*16, w*16+16) ----
      f32x4 sacc[4] = {zero4, zero4, zero4, zero4};
#pragma unroll
      for (int k0 = 0; k0 < DH_; k0 += 32) {
        short8 af = lds8<DH_>(sQ, w * 16 + l15, k0 + g4 * 8);
#pragma unroll
        for (int tc = 0; tc < 4; ++tc) {
          short8 bf = lds8<DH_>(sK, tc * 16 + l15, k0 + g4 * 8);
          sacc[tc] = mfma16(af, bf, sacc[tc]);
        }
      }
      float pv[4][4];
#pragma unroll
      for (int r = 0; r < 4; ++r) {
        float mx = -1e30f;
#pragma unroll
        for (int tc = 0; tc < 4; ++tc) {
          float sv = sacc[tc][r] * 0.125f + amv[tc * 16 + l15];
          pv[tc][r] = sv;
          mx = fmaxf(mx, sv);
        }
        mx = red16max(mx);
        float sm = 0.f;
#pragma unroll
        for (int tc = 0; tc < 4; ++tc) {
          float e = __expf(pv[tc][r] - mx);
          pv[tc][r] = e;
          sm += e;
        }
        sm = red16sum(sm);
        float inv = 1.f / sm;
        int row = w * 16 + g4 * 4 + r;
#pragma unroll
        for (int tc = 0; tc < 4; ++tc)
          ldsw<DH_>(sP, row, tc * 16 + l15, f2b(pv[tc][r] * inv));
      }
      __syncthreads();

      // ---- ctx = P @ V: wave w computes ctx cols [w*16, +16) ----
      f32x4 cacc[4] = {zero4, zero4, zero4, zero4};
#pragma unroll
      for (int k0 = 0; k0 < DH_; k0 += 32) {
        short8 bf = lds8<DH_>(sV, w * 16 + l15, k0 + g4 * 8);
#pragma unroll
        for (int tr = 0; tr < 4; ++tr) {
          short8 af = lds8<DH_>(sP, tr * 16 + l15, k0 + g4 * 8);
          cacc[tr] = mfma16(af, bf, cacc[tr]);
        }
      }
#pragma unroll
      for (int tr = 0; tr < 4; ++tr)
#pragma unroll
        for (int r = 0; r < 4; ++r)
          ldsw<DH_>(sCtx, tr * 16 + g4 * 4 + r, w * 16 + l15, f2b(cacc[tr][r]));
      __syncthreads();

      // ---- O-proj partial: oacc += ctx_h @ ow[h*64.., wave cols] ----
#pragma unroll
      for (int k0 = 0; k0 < DH_; k0 += 32) {
        short8 bfr[4];
#pragma unroll
        for (int tc = 0; tc < 4; ++tc) {
          int colg = w * DH_ + tc * 16 + l15;
          bfr[tc] = *(const short8*)(wo + colg * H_ + h * DH_ + k0 + g4 * 8);
        }
#pragma unroll
        for (int tr = 0; tr < 4; ++tr) {
          short8 af = lds8<DH_>(sCtx, tr * 16 + l15, k0 + g4 * 8);
#pragma unroll
          for (int tc = 0; tc < 4; ++tc) oacc[tr][tc] = mfma16(af, bfr[tc], oacc[tr][tc]);
        }
      }
      __syncthreads();
    }  // heads

    // ---- attn out: + ob + residual x, LayerNorm -> xb ----
    {
#pragma unroll
      for (int tc = 0; tc < 4; ++tc) {
        int col = w * 64 + tc * 16 + l15;
        float obv = ob[ly * H_ + col];
#pragma unroll
        for (int tr = 0; tr < 4; ++tr)
#pragma unroll
          for (int r = 0; r < 4; ++r) {
            int row = tr * 16 + g4 * 4 + r;
            float xv = b2f((unsigned short)xb[(row * H_ + col) ^ ((row & 7) << 3)]);
            oacc[tr][tc][r] += obv + xv;
          }
      }
#pragma unroll
      for (int tr = 0; tr < 4; ++tr)
#pragma unroll
        for (int r = 0; r < 4; ++r) {
          float s1 = 0.f, s2 = 0.f;
#pragma unroll
          for (int tc = 0; tc < 4; ++tc) {
            float v = oacc[tr][tc][r];
            s1 += v; s2 += v * v;
          }
          s1 = red16sum(s1); s2 = red16sum(s2);
          if (l15 == 0) {
            int row = tr * 16 + g4 * 4 + r;
            part[0][row][w] = s1; part[1][row][w] = s2;
          }
        }
      __syncthreads();
      float mean_[4][4], rstd_[4][4];
#pragma unroll
      for (int tr = 0; tr < 4; ++tr)
#pragma unroll
        for (int r = 0; r < 4; ++r) {
          int row = tr * 16 + g4 * 4 + r;
          float s1 = part[0][row][0] + part[0][row][1] + part[0][row][2] + part[0][row][3];
          float s2 = part[1][row][0] + part[1][row][1] + part[1][row][2] + part[1][row][3];
          float mean = s1 * (1.f / H_);
          mean_[tr][r] = mean;
          rstd_[tr][r] = rsqrtf(s2 * (1.f / H_) - mean * mean + 1e-12f);
        }
#pragma unroll
      for (int tc = 0; tc < 4; ++tc) {
        int col = w * 64 + tc * 16 + l15;
        float gv = attn_g[ly * H_ + col], bv = attn_b[ly * H_ + col];
#pragma unroll
        for (int tr = 0; tr < 4; ++tr)
#pragma unroll
          for (int r = 0; r < 4; ++r) {
            int row = tr * 16 + g4 * 4 + r;
            float av = (oacc[tr][tc][r] - mean_[tr][r]) * rstd_[tr][r] * gv + bv;
            xb[(row * H_ + col) ^ ((row & 7) << 3)] = (short)f2b(av);
          }
      }
      __syncthreads();
    }

    // ======== FFN: gelu(a @ iw + ib) @ outw, in 4 chunks of 128 I-cols ========
    f32x4 o2[4][4];
#pragma unroll
    for (int a = 0; a < 4; ++a)
#pragma unroll
      for (int b = 0; b < 4; ++b) o2[a][b] = zero4;

    for (int c = 0; c < 4; ++c) {
      f32x4 hacc[4][2];
#pragma unroll
      for (int a = 0; a < 4; ++a) { hacc[a][0] = zero4; hacc[a][1] = zero4; }
#pragma unroll
      for (int k0 = 0; k0 < H_; k0 += 32) {
        short8 bfr[2];
#pragma unroll
        for (int t2 = 0; t2 < 2; ++t2) {
          int col = c * 128 + w * 32 + t2 * 16 + l15;
          bfr[t2] = *(const short8*)(wii + col * H_ + k0 + g4 * 8);
        }
#pragma unroll
        for (int tr = 0; tr < 4; ++tr) {
          short8 af = lds8<H_>(xb, tr * 16 + l15, k0 + g4 * 8);
          hacc[tr][0] = mfma16(af, bfr[0], hacc[tr][0]);
          hacc[tr][1] = mfma16(af, bfr[1], hacc[tr][1]);
        }
      }
#pragma unroll
      for (int t2 = 0; t2 < 2; ++t2) {
        int col = c * 128 + w * 32 + t2 * 16 + l15;
        float ibv = ib[ly * I_ + col];
#pragma unroll
        for (int tr = 0; tr < 4; ++tr)
#pragma unroll
          for (int r = 0; r < 4; ++r) {
            float v = hacc[tr][t2][r] + ibv;
            v = 0.5f * v * (1.f + erff(v * 0.70710678118f));
            ldsw<128>(sH, tr * 16 + g4 * 4 + r, w * 32 + t2 * 16 + l15, f2b(v));
          }
      }
      __syncthreads();
#pragma unroll
      for (int k0 = 0; k0 < 128; k0 += 32) {
        short8 bfr[4];
#pragma unroll
        for (int tc = 0; tc < 4; ++tc) {
          int col = w * 64 + tc * 16 + l15;
          bfr[tc] = *(const short8*)(wou + col * I_ + c * 128 + k0 + g4 * 8);
        }
#pragma unroll
        for (int tr = 0; tr < 4; ++tr) {
          short8 af = lds8<128>(sH, tr * 16 + l15, k0 + g4 * 8);
#pragma unroll
          for (int tc = 0; tc < 4; ++tc) o2[tr][tc] = mfma16(af, bfr[tc], o2[tr][tc]);
        }
      }
      __syncthreads();
    }

    // ---- FFN out: + outb + residual a, LayerNorm -> xb ----
    {
#pragma unroll
      for (int tc = 0; tc < 4; ++tc) {
        int col = w * 64 + tc * 16 + l15;
        float obv = outb[ly * H_ + col];
#pragma unroll
        for (int tr = 0; tr < 4; ++tr)
#pragma unroll
          for (int r = 0; r < 4; ++r) {
            int row = tr * 16 + g4 * 4 + r;
            float xv = b2f((unsigned short)xb[(row * H_ + col) ^ ((row & 7) << 3)]);
            o2[tr][tc][r] += obv + xv;
          }
      }
#pragma unroll
      for (int tr = 0; tr < 4; ++tr)
#pragma unroll
        for (int r = 0; r < 4; ++r) {
          float s1 = 0.f, s2 = 0.f;
#pragma unroll
          for (int tc = 0; tc < 4; ++tc) {
            float v = o2[tr][tc][r];
            s1 += v; s2 += v * v;
          }
          s1 = red16sum(s1); s2 = red16sum(s2);
          if (l15 == 0) {
            int row = tr * 16 + g4 * 4 + r;
            part[0][row][w] = s1; part[1][row][w] = s2;
          }
        }
      __syncthreads();
      float mean_[4][4], rstd_[4][4];
#pragma unroll
      for (int tr = 0; tr < 4; ++tr)
#pragma unroll
        for (int r = 0; r < 4; ++r) {
          int row = tr * 16 + g4 * 4 + r;
          float s1 = part[0][row][0] + part[0][row][1] + part[0][row][2] + part[0][row][3];
          float s2 = part[1][row][0] + part[1][row][1] + part[1][row][2] + part[1][row][3];
          float mean = s1 * (1.f / H_);
          mean_[tr][r] = mean;
          rstd_[tr][r] = rsqrtf(s2 * (1.f / H_) - mean * mean + 1e-12f);
        }
#pragma unroll
      for (int tc = 0; tc < 4; ++tc) {
        int col = w * 64 + tc * 16 + l15;
        float gv = out_g[ly * H_ + col], bv = out_b[ly * H_ + col];
#pragma unroll
        for (int tr = 0; tr < 4; ++tr)
#pragma unroll
          for (int r = 0; r < 4; ++r) {
            int row = tr * 16 + g4 * 4 + r;
            float av = (o2[tr][tc][r] - mean_[tr][r]) * rstd_[tr][r] * gv + bv;
            xb[(row * H_ + col) ^ ((row & 7) << 3)] = (short)f2b(av);
          }
      }
      __syncthreads();
    }
  }  // layers

  // ---- pooler: out[n] = tanh(x[0] @ pool_w + pool_b); thread = out col ----
  {
    float acc = pool_b[tid];
#pragma unroll 8
    for (int k = 0; k < H_; ++k) {
      float xv = b2f((unsigned short)xb[k]);  // row 0: swizzle is identity
      acc += xv * pool_w[k * H_ + tid];
    }
    out[n * H_ + tid] = tanhf(acc);
  }
}

extern "C" void kernel_launch(void* const* d_in, const int* in_sizes, int n_in,
                              void* d_out, int out_size, void* d_ws, size_t ws_size,
                              hipStream_t stream) {
  const int* word = (const int*)d_in[0];
  const int* age = (const int*)d_in[1];
  const int* seg = (const int*)d_in[2];
  const int* posi = (const int*)d_in[3];
  const float* mask = (const float*)d_in[4];
  // d_in[5] = token (unused by reference output path)
  const float* word_emb = (const float*)d_in[6];
  const float* seg_emb = (const float*)d_in[7];
  const float* age_emb = (const float*)d_in[8];
  const float* posi_emb = (const float*)d_in[9];
  const float* emb_g = (const float*)d_in[10];
  const float* emb_b = (const float*)d_in[11];
  const float* qw = (const float*)d_in[12];
  const float* qb = (const float*)d_in[13];
  const float* kw = (const float*)d_in[14];
  const float* kb = (const float*)d_in[15];
  const float* vw = (const float*)d_in[16];
  const float* vb = (const float*)d_in[17];
  const float* ow = (const float*)d_in[18];
  const float* ob = (const float*)d_in[19];
  const float* attn_g = (const float*)d_in[20];
  const float* attn_b = (const float*)d_in[21];
  const float* iw = (const float*)d_in[22];
  const float* ib = (const float*)d_in[23];
  const float* outw = (const float*)d_in[24];
  const float* outb = (const float*)d_in[25];
  const float* out_g = (const float*)d_in[26];
  const float* out_b = (const float*)d_in[27];
  const float* pool_w = (const float*)d_in[28];
  const float* pool_b = (const float*)d_in[29];
  short* ws = (short*)d_ws;

  prep_w<<<4096, 256, 0, stream>>>(qw, kw, vw, ow, iw, outw, ws);
  bert_fused<<<1600, 256, 0, stream>>>(
      word, age, seg, posi, mask, word_emb, seg_emb, age_emb, posi_emb,
      emb_g, emb_b, qb, kb, vb, ob, attn_g, attn_b, ib, outb, out_g, out_b,
      pool_w, pool_b,
      ws, ws + 131072, ws + 262144, ws + 393216, ws + 524288, ws + 786432,
      (float*)d_out);
}

// Round 3
// 1300.919 us; speedup vs baseline: 1.0491x; 1.0491x over previous
//
#include <hip/hip_runtime.h>
#include <math.h>

#define S_ 64
#define H_ 256
#define NH_ 4
#define DH_ 64
#define I_ 512
#define L_ 2

typedef __attribute__((ext_vector_type(8))) short short8;
typedef __attribute__((ext_vector_type(4))) short short4v;
typedef __attribute__((ext_vector_type(4))) float f32x4;

__device__ __forceinline__ unsigned short f2b(float f) {
  unsigned u = __float_as_uint(f);
  return (unsigned short)((u + 0x7fffu + ((u >> 16) & 1u)) >> 16);
}
__device__ __forceinline__ float b2f(unsigned short h) {
  return __uint_as_float(((unsigned)h) << 16);
}
__device__ __forceinline__ f32x4 mfma16(short8 a, short8 b, f32x4 c) {
  return __builtin_amdgcn_mfma_f32_16x16x32_bf16(a, b, c, 0, 0, 0);
}
// XOR-swizzled LDS tiles: element (row,col) at (row*STRIDE+col)^((row&7)<<3)
template <int STRIDE>
__device__ __forceinline__ short8 lds8(const short* buf, int row, int k) {
  int idx = (row * STRIDE + k) ^ ((row & 7) << 3);
  return *(const short8*)(buf + idx);
}
template <int STRIDE>
__device__ __forceinline__ void ldsw(short* buf, int row, int col, unsigned short v) {
  buf[(row * STRIDE + col) ^ ((row & 7) << 3)] = (short)v;
}
__device__ __forceinline__ float red16sum(float v) {
  v += __shfl_xor(v, 1); v += __shfl_xor(v, 2);
  v += __shfl_xor(v, 4); v += __shfl_xor(v, 8);
  return v;
}
__device__ __forceinline__ float red16max(float v) {
  v = fmaxf(v, __shfl_xor(v, 1)); v = fmaxf(v, __shfl_xor(v, 2));
  v = fmaxf(v, __shfl_xor(v, 4)); v = fmaxf(v, __shfl_xor(v, 8));
  return v;
}

// ---- weight prep: f32 [K][N] -> bf16 WT[N][K] (per layer), packed into ws ----
__global__ void prep_w(const float* __restrict__ qw, const float* __restrict__ kw,
                       const float* __restrict__ vw, const float* __restrict__ ow,
                       const float* __restrict__ iw, const float* __restrict__ outw,
                       short* __restrict__ ws) {
  int t = blockIdx.x * 256 + threadIdx.x;  // 1,048,576 total
  if (t < 524288) {
    int which = t >> 17;
    int r = t & 131071;
    int l = r >> 16, rr = r & 65535;
    int col = rr >> 8, k = rr & 255;
    const float* m = which == 0 ? qw : which == 1 ? kw : which == 2 ? vw : ow;
    ws[t] = (short)f2b(m[(l * 256 + k) * 256 + col]);
  } else if (t < 786432) {
    int tp = t - 524288;
    int l = tp >> 17, rr = tp & 131071;
    int col = rr >> 8, k = rr & 255;
    ws[t] = (short)f2b(iw[(l * 256 + k) * 512 + col]);
  } else {
    int tp = t - 786432;
    int l = tp >> 17, rr = tp & 131071;
    int col = rr >> 9, k = rr & 511;
    ws[t] = (short)f2b(outw[(l * 512 + k) * 256 + col]);
  }
}

// ---- fused BERT: 1 workgroup = 1 sequence; wave w owns q-rows [16w,16w+16) ----
// __launch_bounds__(256) (no min-waves): ~200 VGPR, no spill; 129-256 VGPR band
// still gives 2 waves/SIMD = 2 blocks/CU, which equals the LDS (68KB) limit.
__global__ __launch_bounds__(256) void bert_fused(
    const int* __restrict__ word, const int* __restrict__ age,
    const int* __restrict__ seg, const int* __restrict__ posi,
    const float* __restrict__ mask,
    const float* __restrict__ word_emb, const float* __restrict__ seg_emb,
    const float* __restrict__ age_emb, const float* __restrict__ posi_emb,
    const float* __restrict__ emb_g, const float* __restrict__ emb_b,
    const float* __restrict__ qb, const float* __restrict__ kb,
    const float* __restrict__ vb, const float* __restrict__ ob,
    const float* __restrict__ attn_g, const float* __restrict__ attn_b,
    const float* __restrict__ ib, const float* __restrict__ outb,
    const float* __restrict__ out_g, const float* __restrict__ out_b,
    const float* __restrict__ pool_w, const float* __restrict__ pool_b,
    const short* __restrict__ wsq, const short* __restrict__ wsk,
    const short* __restrict__ wsv, const short* __restrict__ wso,
    const short* __restrict__ wsi, const short* __restrict__ wsout,
    float* __restrict__ out) {
  __shared__ __align__(16) short xb[S_ * H_];    // residual stream (32KB)
  __shared__ __align__(16) short arena[S_ * H_]; // attn: Q|K|V (24KB) / FFN: h dbuf (32KB)
  __shared__ __align__(16) short scr[4096];      // per-wave 2KB transpose scratch
  __shared__ float part[2][S_][NH_];

  short* sQ = arena;            // 64x64 row-major (swz)
  short* sK = arena + 4096;     // 64x64 row-major (swz)
  short* sV = arena + 8192;     // V^T: [dh][kseq] (swz)
  short* sH0 = arena;           // FFN chunk buffers (64x128 each)
  short* sH1 = arena + 8192;

  const int n = blockIdx.x;
  const int tid = threadIdx.x;
  const int w = tid >> 6;
  const int lane = tid & 63;
  const int l15 = lane & 15;
  const int g4 = lane >> 4;
  const f32x4 zero4 = {0.f, 0.f, 0.f, 0.f};
  short* sW = scr + w * 1024;   // 16x64 per-wave

  float amvr[4];
#pragma unroll
  for (int tc = 0; tc < 4; ++tc)
    amvr[tc] = (1.f - mask[n * S_ + tc * 16 + l15]) * -10000.f;

  // ---- embedding + LayerNorm (indices prefetched, broadcast via shfl) ----
  {
    int bi = n * S_ + w * 16 + l15;
    int wiv = word[bi], siv = seg[bi], aiv = age[bi], piv = posi[bi];
#pragma unroll 2
    for (int i = 0; i < 16; ++i) {
      int s = w * 16 + i;
      int wi = __shfl(wiv, i), gi = __shfl(siv, i);
      int ai = __shfl(aiv, i), pi = __shfl(piv, i);
      f32x4 e = ((const f32x4*)(word_emb + wi * H_))[lane];
      f32x4 t = ((const f32x4*)(seg_emb + gi * H_))[lane]; e = e + t;
      t = ((const f32x4*)(age_emb + ai * H_))[lane]; e = e + t;
      t = ((const f32x4*)(posi_emb + pi * H_))[lane]; e = e + t;
      float s1 = e[0] + e[1] + e[2] + e[3];
      float s2 = e[0] * e[0] + e[1] * e[1] + e[2] * e[2] + e[3] * e[3];
      for (int m = 1; m < 64; m <<= 1) { s1 += __shfl_xor(s1, m); s2 += __shfl_xor(s2, m); }
      float mean = s1 * (1.f / H_);
      float rstd = rsqrtf(s2 * (1.f / H_) - mean * mean + 1e-12f);
      f32x4 gv = ((const f32x4*)emb_g)[lane];
      f32x4 bv = ((const f32x4*)emb_b)[lane];
      short4v pk;
#pragma unroll
      for (int j = 0; j < 4; ++j) pk[j] = (short)f2b((e[j] - mean) * rstd * gv[j] + bv[j]);
      int idx = (s * H_ + lane * 4) ^ ((s & 7) << 3);
      *(short4v*)(xb + idx) = pk;
    }
  }
  __syncthreads();

  for (int ly = 0; ly < L_; ++ly) {
    const short* wq = wsq + ly * H_ * H_;
    const short* wk = wsk + ly * H_ * H_;
    const short* wv = wsv + ly * H_ * H_;
    const short* wo = wso + ly * H_ * H_;
    const short* wii = wsi + ly * I_ * H_;
    const short* wou = wsout + ly * H_ * I_;

    // O accumulator: wave's 16 rows x 256 cols (16 col-tiles)
    f32x4 oacc[16];
#pragma unroll
    for (int a = 0; a < 16; ++a) oacc[a] = zero4;

    // ======== attention ========
    for (int h = 0; h < NH_; ++h) {
      // ---- QKV (cooperative col-strips, hoisted weight loads) ----
      for (int m3 = 0; m3 < 3; ++m3) {
        const short* wt = m3 == 0 ? wq : (m3 == 1 ? wk : wv);
        const float* bs = m3 == 0 ? qb : (m3 == 1 ? kb : vb);
        int colg = h * DH_ + w * 16 + l15;
        float bias = bs[ly * H_ + colg];
        short8 bfv[8];
#pragma unroll
        for (int kk = 0; kk < 8; ++kk)
          bfv[kk] = *(const short8*)(wt + colg * H_ + kk * 32 + g4 * 8);
        f32x4 acc[4] = {zero4, zero4, zero4, zero4};
#pragma unroll
        for (int kk = 0; kk < 8; ++kk) {
#pragma unroll
          for (int tr = 0; tr < 4; ++tr) {
            short8 af = lds8<H_>(xb, tr * 16 + l15, kk * 32 + g4 * 8);
            acc[tr] = mfma16(af, bfv[kk], acc[tr]);
          }
        }
        if (m3 == 0) {
#pragma unroll
          for (int tr = 0; tr < 4; ++tr)
#pragma unroll
            for (int r = 0; r < 4; ++r)
              ldsw<DH_>(sQ, tr * 16 + g4 * 4 + r, w * 16 + l15, f2b(acc[tr][r] + bias));
        } else if (m3 == 1) {
#pragma unroll
          for (int tr = 0; tr < 4; ++tr)
#pragma unroll
            for (int r = 0; r < 4; ++r)
              ldsw<DH_>(sK, tr * 16 + g4 * 4 + r, w * 16 + l15, f2b(acc[tr][r] + bias));
        } else {
#pragma unroll
          for (int tr = 0; tr < 4; ++tr)
#pragma unroll
            for (int r = 0; r < 4; ++r)
              ldsw<DH_>(sV, w * 16 + l15, tr * 16 + g4 * 4 + r, f2b(acc[tr][r] + bias));
        }
      }
      __syncthreads();

      // ---- scores: wave w owns q-rows [16w,16w+16) ----
      short8 qa[2];
#pragma unroll
      for (int ks = 0; ks < 2; ++ks) qa[ks] = lds8<DH_>(sQ, w * 16 + l15, ks * 32 + g4 * 8);
      f32x4 sacc[4] = {zero4, zero4, zero4, zero4};
#pragma unroll
      for (int ks = 0; ks < 2; ++ks)
#pragma unroll
        for (int tc = 0; tc < 4; ++tc) {
          short8 kf = lds8<DH_>(sK, tc * 16 + l15, ks * 32 + g4 * 8);
          sacc[tc] = mfma16(qa[ks], kf, sacc[tc]);
        }
      // softmax over kseq (wave-local, rows g4*4+r)
#pragma unroll
      for (int r = 0; r < 4; ++r) {
        float pv[4];
        float mx = -1e30f;
#pragma unroll
        for (int tc = 0; tc < 4; ++tc) {
          float sv = sacc[tc][r] * 0.125f + amvr[tc];
          pv[tc] = sv;
          mx = fmaxf(mx, sv);
        }
        mx = red16max(mx);
        float sm = 0.f;
#pragma unroll
        for (int tc = 0; tc < 4; ++tc) {
          float e = __expf(pv[tc] - mx);
          pv[tc] = e;
          sm += e;
        }
        sm = red16sum(sm);
        float inv = 1.f / sm;
#pragma unroll
        for (int tc = 0; tc < 4; ++tc)
          ldsw<DH_>(sW, g4 * 4 + r, tc * 16 + l15, f2b(pv[tc] * inv));
      }
      __syncthreads();  // order P write -> P read (conservative: same-wave RAW)
      short8 pa[2];
#pragma unroll
      for (int ks = 0; ks < 2; ++ks) pa[ks] = lds8<DH_>(sW, l15, ks * 32 + g4 * 8);
      f32x4 cacc[4] = {zero4, zero4, zero4, zero4};
#pragma unroll
      for (int ks = 0; ks < 2; ++ks)
#pragma unroll
        for (int tc = 0; tc < 4; ++tc) {
          short8 vf = lds8<DH_>(sV, tc * 16 + l15, ks * 32 + g4 * 8);
          cacc[tc] = mfma16(pa[ks], vf, cacc[tc]);
        }
      __syncthreads();  // all pa reads done before ctx overwrites sW
      // ctx transpose (wave-local)
#pragma unroll
      for (int tc = 0; tc < 4; ++tc)
#pragma unroll
        for (int r = 0; r < 4; ++r)
          ldsw<DH_>(sW, g4 * 4 + r, tc * 16 + l15, f2b(cacc[tc][r]));
      __syncthreads();  // order ctx write -> ctx read
      short8 ca[2];
#pragma unroll
      for (int ks = 0; ks < 2; ++ks) ca[ks] = lds8<DH_>(sW, l15, ks * 32 + g4 * 8);
      // O-proj partial: oacc += ctx_h @ Wo[h*64.., all 256 cols]
#pragma unroll
      for (int tc2 = 0; tc2 < 16; ++tc2) {
        const short* wp = wo + (tc2 * 16 + l15) * H_ + h * DH_ + g4 * 8;
        short8 b0 = *(const short8*)(wp);
        short8 b1 = *(const short8*)(wp + 32);
        oacc[tc2] = mfma16(ca[0], b0, oacc[tc2]);
        oacc[tc2] = mfma16(ca[1], b1, oacc[tc2]);
      }
      __syncthreads();
    }  // heads

    // ---- attn out: + ob + residual, row-owned LayerNorm -> xb ----
    {
      float obr[16], gr[16], br[16];
#pragma unroll
      for (int tc2 = 0; tc2 < 16; ++tc2) {
        int col = tc2 * 16 + l15;
        obr[tc2] = ob[ly * H_ + col];
        gr[tc2] = attn_g[ly * H_ + col];
        br[tc2] = attn_b[ly * H_ + col];
      }
#pragma unroll
      for (int r = 0; r < 4; ++r) {
        int rowg = w * 16 + g4 * 4 + r;
        float s1 = 0.f, s2 = 0.f;
#pragma unroll
        for (int tc2 = 0; tc2 < 16; ++tc2) {
          int col = tc2 * 16 + l15;
          float o = oacc[tc2][r] + obr[tc2] +
                    b2f((unsigned short)xb[(rowg * H_ + col) ^ ((rowg & 7) << 3)]);
          oacc[tc2][r] = o;
          s1 += o; s2 += o * o;
        }
        s1 = red16sum(s1); s2 = red16sum(s2);
        float mean = s1 * (1.f / H_);
        float rstd = rsqrtf(s2 * (1.f / H_) - mean * mean + 1e-12f);
#pragma unroll
        for (int tc2 = 0; tc2 < 16; ++tc2) {
          int col = tc2 * 16 + l15;
          float av = (oacc[tc2][r] - mean) * rstd * gr[tc2] + br[tc2];
          xb[(rowg * H_ + col) ^ ((rowg & 7) << 3)] = (short)f2b(av);
        }
      }
      __syncthreads();
    }

    // ======== FFN (software-pipelined chunks of 128 I-cols, h double-buffered) ====
    f32x4 o2[4][4];
#pragma unroll
    for (int a = 0; a < 4; ++a)
#pragma unroll
      for (int b = 0; b < 4; ++b) o2[a][b] = zero4;

    auto ffn1 = [&](int c, short* dst) {
      int col0 = c * 128 + w * 32 + l15;
      short8 bq0[8], bq1[8];
#pragma unroll
      for (int kk = 0; kk < 8; ++kk) {
        bq0[kk] = *(const short8*)(wii + col0 * H_ + kk * 32 + g4 * 8);
        bq1[kk] = *(const short8*)(wii + (col0 + 16) * H_ + kk * 32 + g4 * 8);
      }
      f32x4 hacc[4][2];
#pragma unroll
      for (int a = 0; a < 4; ++a) { hacc[a][0] = zero4; hacc[a][1] = zero4; }
#pragma unroll
      for (int kk = 0; kk < 8; ++kk) {
#pragma unroll
        for (int tr = 0; tr < 4; ++tr) {
          short8 af = lds8<H_>(xb, tr * 16 + l15, kk * 32 + g4 * 8);
          hacc[tr][0] = mfma16(af, bq0[kk], hacc[tr][0]);
          hacc[tr][1] = mfma16(af, bq1[kk], hacc[tr][1]);
        }
      }
#pragma unroll
      for (int t2 = 0; t2 < 2; ++t2) {
        int col = col0 + t2 * 16;
        float ibv = ib[ly * I_ + col];
#pragma unroll
        for (int tr = 0; tr < 4; ++tr)
#pragma unroll
          for (int r = 0; r < 4; ++r) {
            float v = hacc[tr][t2][r] + ibv;
            v = 0.5f * v * (1.f + erff(v * 0.70710678118f));
            ldsw<128>(dst, tr * 16 + g4 * 4 + r, w * 32 + t2 * 16 + l15, f2b(v));
          }
      }
    };
    auto ffn2 = [&](int c, const short* src) {
#pragma unroll
      for (int kk = 0; kk < 4; ++kk) {
        short8 bfr[4];
#pragma unroll
        for (int tc = 0; tc < 4; ++tc)
          bfr[tc] = *(const short8*)(wou + (w * 64 + tc * 16 + l15) * I_ + c * 128 + kk * 32 + g4 * 8);
#pragma unroll
        for (int tr = 0; tr < 4; ++tr) {
          short8 af = lds8<128>(src, tr * 16 + l15, kk * 32 + g4 * 8);
#pragma unroll
          for (int tc = 0; tc < 4; ++tc) o2[tr][tc] = mfma16(af, bfr[tc], o2[tr][tc]);
        }
      }
    };

    ffn1(0, sH0);
    __syncthreads();
    for (int c = 0; c < 4; ++c) {
      if (c < 3) ffn1(c + 1, (c & 1) ? sH0 : sH1);
      ffn2(c, (c & 1) ? sH1 : sH0);
      __syncthreads();
    }

    // ---- FFN out: + outb + residual a, LayerNorm (col-strip w/ part[]) -> xb ----
    {
#pragma unroll
      for (int tc = 0; tc < 4; ++tc) {
        int col = w * 64 + tc * 16 + l15;
        float obv = outb[ly * H_ + col];
#pragma unroll
        for (int tr = 0; tr < 4; ++tr)
#pragma unroll
          for (int r = 0; r < 4; ++r) {
            int row = tr * 16 + g4 * 4 + r;
            float xv = b2f((unsigned short)xb[(row * H_ + col) ^ ((row & 7) << 3)]);
            o2[tr][tc][r] += obv + xv;
          }
      }
#pragma unroll
      for (int tr = 0; tr < 4; ++tr)
#pragma unroll
        for (int r = 0; r < 4; ++r) {
          float s1 = 0.f, s2 = 0.f;
#pragma unroll
          for (int tc = 0; tc < 4; ++tc) {
            float v = o2[tr][tc][r];
            s1 += v; s2 += v * v;
          }
          s1 = red16sum(s1); s2 = red16sum(s2);
          if (l15 == 0) {
            int row = tr * 16 + g4 * 4 + r;
            part[0][row][w] = s1; part[1][row][w] = s2;
          }
        }
      __syncthreads();
      float mean_[4][4], rstd_[4][4];
#pragma unroll
      for (int tr = 0; tr < 4; ++tr)
#pragma unroll
        for (int r = 0; r < 4; ++r) {
          int row = tr * 16 + g4 * 4 + r;
          float s1 = part[0][row][0] + part[0][row][1] + part[0][row][2] + part[0][row][3];
          float s2 = part[1][row][0] + part[1][row][1] + part[1][row][2] + part[1][row][3];
          float mean = s1 * (1.f / H_);
          mean_[tr][r] = mean;
          rstd_[tr][r] = rsqrtf(s2 * (1.f / H_) - mean * mean + 1e-12f);
        }
#pragma unroll
      for (int tc = 0; tc < 4; ++tc) {
        int col = w * 64 + tc * 16 + l15;
        float gv = out_g[ly * H_ + col], bv = out_b[ly * H_ + col];
#pragma unroll
        for (int tr = 0; tr < 4; ++tr)
#pragma unroll
          for (int r = 0; r < 4; ++r) {
            int row = tr * 16 + g4 * 4 + r;
            float av = (o2[tr][tc][r] - mean_[tr][r]) * rstd_[tr][r] * gv + bv;
            xb[(row * H_ + col) ^ ((row & 7) << 3)] = (short)f2b(av);
          }
      }
      __syncthreads();
    }
  }  // layers

  // ---- pooler: out[n] = tanh(x[0] @ pool_w + pool_b); thread = out col ----
  {
    float acc = pool_b[tid];
#pragma unroll 8
    for (int k = 0; k < H_; ++k) {
      float xv = b2f((unsigned short)xb[k]);  // row 0: swizzle is identity
      acc += xv * pool_w[k * H_ + tid];
    }
    out[n * H_ + tid] = tanhf(acc);
  }
}

extern "C" void kernel_launch(void* const* d_in, const int* in_sizes, int n_in,
                              void* d_out, int out_size, void* d_ws, size_t ws_size,
                              hipStream_t stream) {
  const int* word = (const int*)d_in[0];
  const int* age = (const int*)d_in[1];
  const int* seg = (const int*)d_in[2];
  const int* posi = (const int*)d_in[3];
  const float* mask = (const float*)d_in[4];
  const float* word_emb = (const float*)d_in[6];
  const float* seg_emb = (const float*)d_in[7];
  const float* age_emb = (const float*)d_in[8];
  const float* posi_emb = (const float*)d_in[9];
  const float* emb_g = (const float*)d_in[10];
  const float* emb_b = (const float*)d_in[11];
  const float* qw = (const float*)d_in[12];
  const float* qb = (const float*)d_in[13];
  const float* kw = (const float*)d_in[14];
  const float* kb = (const float*)d_in[15];
  const float* vw = (const float*)d_in[16];
  const float* vb = (const float*)d_in[17];
  const float* ow = (const float*)d_in[18];
  const float* ob = (const float*)d_in[19];
  const float* attn_g = (const float*)d_in[20];
  const float* attn_b = (const float*)d_in[21];
  const float* iw = (const float*)d_in[22];
  const float* ib = (const float*)d_in[23];
  const float* outw = (const float*)d_in[24];
  const float* outb = (const float*)d_in[25];
  const float* out_g = (const float*)d_in[26];
  const float* out_b = (const float*)d_in[27];
  const float* pool_w = (const float*)d_in[28];
  const float* pool_b = (const float*)d_in[29];
  short* ws = (short*)d_ws;

  prep_w<<<4096, 256, 0, stream>>>(qw, kw, vw, ow, iw, outw, ws);
  bert_fused<<<1600, 256, 0, stream>>>(
      word, age, seg, posi, mask, word_emb, seg_emb, age_emb, posi_emb,
      emb_g, emb_b, qb, kb, vb, ob, attn_g, attn_b, ib, outb, out_g, out_b,
      pool_w, pool_b,
      ws, ws + 131072, ws + 262144, ws + 393216, ws + 524288, ws + 786432,
      (float*)d_out);
}